// Round 13
// baseline (86.770 us; speedup 1.0000x reference)
//
#include <hip/hip_runtime.h>
#include <math.h>

#define BATCH 512
#define NPTS  512

// Rotate a float ACROSS the full wave64 so that dst[l] = src[(l+1) & 63].
// DPP ctrl 0x134 = wave_rol:1 (verified R6-R12).
__device__ __forceinline__ float rot1(float v) {
    return __int_as_float(__builtin_amdgcn_update_dpp(
        __float_as_int(v), __float_as_int(v), 0x134, 0xF, 0xF, false));
}

// EXACT deg-7 path (LUT build only): w(d) = exp2(-acos(d)*log2e).
__device__ __forceinline__ float pair_w_exact(float d) {
    d = __builtin_amdgcn_fmed3f(d, -1.f, 1.f);
    float a  = fabsf(d);
    float t  = 1.f - a;
    float sq = __builtin_amdgcn_sqrtf(t);
    float p  = fmaf(-0.00182139f, a, 0.00962291f);
    p = fmaf(p, a, -0.02465296f);
    p = fmaf(p, a,  0.04456757f);
    p = fmaf(p, a, -0.07238623f);
    p = fmaf(p, a,  0.12836958f);
    p = fmaf(p, a, -0.30960063f);
    p = fmaf(p, a,  2.26618007f);
    float q = sq * p;
    float e = (d < 0.f) ? (4.53236014f - q) : q;
    return __builtin_amdgcn_exp2f(-e);
}

// NN LUT, 1025 cells over [-1,1], replicated 4x interleaved (R12-verified,
// absmax 0.0039). Index clamp doubles as the d-clamp.
__device__ __forceinline__ float pair_w(float d, const float* __restrict__ wtab,
                                        int c4) {
    float idx_f = __builtin_amdgcn_fmed3f(fmaf(d, 512.f, 512.5f), 0.f, 1024.f);
    return wtab[(((int)idx_f) << 2) + c4];
}

// Segment vs B-chunk v, steps k=K0..K1 (pair: lane l vs B_{(l+k)&63}).
// B chunk + traveling transpose accumulator rotate in registers (R6-verified).
template<int K0, int K1, bool TAIL>
__device__ __forceinline__ void do_seg(
    const float* __restrict__ sx, const float* __restrict__ sy,
    const float* __restrict__ sz, const float* __restrict__ wtab,
    int v, int lane, int c4, float xi, float yi, float zi,
    float& accA, float* __restrict__ racc)
{
    const int bi = v * 64 + lane;
    float bx = sx[bi], by = sy[bi], bz = sz[bi];
    float bacc = 0.f;
    #pragma unroll
    for (int r = 0; r < K0; ++r) { bx = rot1(bx); by = rot1(by); bz = rot1(bz); }
    #pragma unroll 16
    for (int k = K0; k <= K1; ++k) {
        float d = fmaf(xi, bx, fmaf(yi, by, zi * bz));
        float w = pair_w(d, wtab, c4);
        accA += w;            // row i
        bacc += w;            // row (i+k) — traveling register
        bx = rot1(bx); by = rot1(by); bz = rot1(bz); bacc = rot1(bacc);
    }
    if (TAIL) {               // alignment K1+1, own-row only (self-chunk k=32)
        float d = fmaf(xi, bx, fmaf(yi, by, zi * bz));
        accA += pair_w(d, wtab, c4);
    }
    const int m = (lane + K1 + 1) & 63;  // home slot of bacc after rotations
    atomicAdd(&racc[v * 64 + m], bacc);
}

// FOUR blocks per batch (R13): grid 2048 = 8 blocks/CU of work -> 4 resident
// + backfill, so CUs stay saturated through block drain (R12 measured only
// 52% occupancy with grid==capacity and no backfill). Quarters are balanced
// 64-step re-partitions of the R6-verified schedule:
//   Q0 = self(k=1..31,+tail32) + {w,w+-4} split   (32+32)
//   Q1/Q2/Q3 = full cross pair (+1)/(+2)/(+3)     (64 each)
__global__ __launch_bounds__(512, 8) void pairs_kernel(
    const float* __restrict__ normals, float* __restrict__ ws)
{
    __shared__ float sx[NPTS], sy[NPTS], sz[NPTS];
    __shared__ float racc[NPTS];
    __shared__ float wtab[4 * 1025];
    __shared__ float rx[8], ry[8], rz[8];
    const int bx_id = blockIdx.x;
    const int b     = bx_id >> 2, quarter = bx_id & 3;
    const int tid   = threadIdx.x;
    const int wave  = tid >> 6, lane = tid & 63;
    const int c4    = lane & 3;
    const float* base = normals + (size_t)b * NPTS * 3;

    // Build the replicated w(d) table (one-time; exact poly path).
    for (int e = tid; e < 1025; e += NPTS) {
        float w = pair_w_exact((float)e * (1.f / 512.f) - 1.f);
        int b4 = e << 2;
        wtab[b4] = w; wtab[b4 + 1] = w; wtab[b4 + 2] = w; wtab[b4 + 3] = w;
    }
    for (int k = tid; k < NPTS * 3; k += NPTS) {
        float val = base[k];
        int r = k / 3, c = k - r * 3;
        float* dst = (c == 0) ? sx : (c == 1) ? sy : sz;
        dst[r] = val;
    }
    racc[tid] = 0.f;
    __syncthreads();

    const float xi = sx[tid], yi = sy[tid], zi = sz[tid];
    float accA = 0.f;

    if (quarter == 0) {
        do_seg<1, 31, true >(sx, sy, sz, wtab, wave, lane, c4, xi, yi, zi, accA, racc);
        if (wave < 4) do_seg<0, 31, false>(sx, sy, sz, wtab, wave + 4, lane, c4, xi, yi, zi, accA, racc);
        else          do_seg<1, 32, false>(sx, sy, sz, wtab, wave - 4, lane, c4, xi, yi, zi, accA, racc);
    } else if (quarter == 1) {
        do_seg<0, 63, false>(sx, sy, sz, wtab, (wave + 1) & 7, lane, c4, xi, yi, zi, accA, racc);
    } else if (quarter == 2) {
        do_seg<0, 63, false>(sx, sy, sz, wtab, (wave + 2) & 7, lane, c4, xi, yi, zi, accA, racc);
    } else {
        do_seg<0, 63, false>(sx, sy, sz, wtab, (wave + 3) & 7, lane, c4, xi, yi, zi, accA, racc);
    }

    __syncthreads();
    float s = accA + racc[tid];   // partial row sum (this block's pairs only)

    // Global-max division skipped: uniform positive scale cancels under the
    // final normalization (verified R0-R12).
    float ax = s * xi, ay = s * yi, az = s * zi;

    for (int off = 32; off > 0; off >>= 1) {
        ax += __shfl_down(ax, off, 64);
        ay += __shfl_down(ay, off, 64);
        az += __shfl_down(az, off, 64);
    }
    if (lane == 0) { rx[wave] = ax; ry[wave] = ay; rz[wave] = az; }
    __syncthreads();

    if (tid == 0) {
        float nx = 0.f, ny = 0.f, nz = 0.f;
        #pragma unroll
        for (int w = 0; w < 8; ++w) { nx += rx[w]; ny += ry[w]; nz += rz[w]; }
        ((float4*)ws)[bx_id] = make_float4(nx, ny, nz, 0.f);  // no atomics
    }
}

__global__ __launch_bounds__(512) void norm_kernel(
    const float* __restrict__ ws, float* __restrict__ out)
{
    const int t = threadIdx.x;    // one thread per batch
    float4 p0 = ((const float4*)ws)[4 * t];
    float4 p1 = ((const float4*)ws)[4 * t + 1];
    float4 p2 = ((const float4*)ws)[4 * t + 2];
    float4 p3 = ((const float4*)ws)[4 * t + 3];
    float nx = (p0.x + p1.x) + (p2.x + p3.x);
    float ny = (p0.y + p1.y) + (p2.y + p3.y);
    float nz = (p0.z + p1.z) + (p2.z + p3.z);
    float len2 = fmaf(nx, nx, fmaf(ny, ny, nz * nz));
    float inv  = rsqrtf(fmaxf(len2, 1e-20f));
    out[t * 3 + 0] = nx * inv;
    out[t * 3 + 1] = ny * inv;
    out[t * 3 + 2] = nz * inv;
}

extern "C" void kernel_launch(void* const* d_in, const int* in_sizes, int n_in,
                              void* d_out, int out_size, void* d_ws, size_t ws_size,
                              hipStream_t stream) {
    const float* normals = (const float*)d_in[0];
    // d_in[1] (weights) is mathematically unused by the reference.
    float* out = (float*)d_out;
    float* ws  = (float*)d_ws;
    pairs_kernel<<<4 * BATCH, NPTS, 0, stream>>>(normals, ws);
    norm_kernel<<<1, BATCH, 0, stream>>>(ws, out);
}

// Round 14
// 82.901 us; speedup vs baseline: 1.0467x; 1.0467x over previous
//
#include <hip/hip_runtime.h>
#include <math.h>

#define BATCH 512
#define NPTS  512

// Rotate a float ACROSS the full wave64 so that dst[l] = src[(l+1) & 63].
// DPP ctrl 0x134 = wave_rol:1 (verified R6-R13).
__device__ __forceinline__ float rot1(float v) {
    return __int_as_float(__builtin_amdgcn_update_dpp(
        __float_as_int(v), __float_as_int(v), 0x134, 0xF, 0xF, false));
}

// EXACT path (used only to build the LUT): w(d) = exp2(-acos(d)*log2e),
// A&S 4.4.46 deg-7 poly pre-scaled by log2(e). Verified absmax 0.0 (R2-R6).
// Exact at endpoints: d=1 -> 1, d=-1 -> e^-pi.
__device__ __forceinline__ float pair_w_exact(float d) {
    d = __builtin_amdgcn_fmed3f(d, -1.f, 1.f);
    float a  = fabsf(d);
    float t  = 1.f - a;
    float sq = __builtin_amdgcn_sqrtf(t);
    float p  = fmaf(-0.00182139f, a, 0.00962291f);
    p = fmaf(p, a, -0.02465296f);
    p = fmaf(p, a,  0.04456757f);
    p = fmaf(p, a, -0.07238623f);
    p = fmaf(p, a,  0.12836958f);
    p = fmaf(p, a, -0.30960063f);
    p = fmaf(p, a,  2.26618007f);
    float q = sq * p;
    float e = (d < 0.f) ? (4.53236014f - q) : q;
    return __builtin_amdgcn_exp2f(-e);
}

// Nearest-neighbor LUT: 2049 f32 entries over [-1,1] (cell 1/1024).
// Index clamp doubles as the d-clamp (d>1 -> 2048 exact, d<-1 -> 0 exact).
// 4 VALU ops + one ds_read_b32 that feeds only the accumulate.
// (R12 4x bank replication measured NULL vs this — same-address hot entries
// broadcast for free; random-idx conflicts are the physics floor.)
__device__ __forceinline__ float pair_w(float d, const float* __restrict__ wtab) {
    float idx_f = __builtin_amdgcn_fmed3f(fmaf(d, 1024.f, 1024.5f), 0.f, 2048.f);
    return wtab[(int)idx_f];
}

// Segment vs B-chunk v, steps k=K0..K1 (pair: lane l vs B_{(l+k)&63}).
// B chunk + traveling transpose accumulator rotate in registers (R6-verified).
template<int K0, int K1, bool TAIL>
__device__ __forceinline__ void do_seg(
    const float* __restrict__ sx, const float* __restrict__ sy,
    const float* __restrict__ sz, const float* __restrict__ wtab,
    int v, int lane, float xi, float yi, float zi,
    float& accA, float* __restrict__ racc)
{
    const int bi = v * 64 + lane;
    float bx = sx[bi], by = sy[bi], bz = sz[bi];
    float bacc = 0.f;
    #pragma unroll
    for (int r = 0; r < K0; ++r) { bx = rot1(bx); by = rot1(by); bz = rot1(bz); }
    #pragma unroll 16
    for (int k = K0; k <= K1; ++k) {
        float d = fmaf(xi, bx, fmaf(yi, by, zi * bz));
        float w = pair_w(d, wtab);
        accA += w;            // row i
        bacc += w;            // row (i+k) — traveling register
        bx = rot1(bx); by = rot1(by); bz = rot1(bz); bacc = rot1(bacc);
    }
    if (TAIL) {               // alignment K1+1, own-row only (self-chunk k=32)
        float d = fmaf(xi, bx, fmaf(yi, by, zi * bz));
        accA += pair_w(d, wtab);
    }
    const int m = (lane + K1 + 1) & 63;  // home slot of bacc after rotations
    atomicAdd(&racc[v * 64 + m], bacc);
}

// Two blocks per batch (R8): grid 1024 = 4 blocks/CU = 8 waves/SIMD.
// (R13's 4 blocks/batch regressed: fixed per-block costs doubled for no
// occupancy gain. This is the empirically best partition.)
__global__ __launch_bounds__(512, 8) void pairs_kernel(
    const float* __restrict__ normals, float* __restrict__ ws)
{
    __shared__ float sx[NPTS], sy[NPTS], sz[NPTS];
    __shared__ float racc[NPTS];
    __shared__ float wtab[2049];
    __shared__ float rx[8], ry[8], rz[8];
    const int bx_id = blockIdx.x;
    const int b     = bx_id >> 1, half = bx_id & 1;
    const int tid   = threadIdx.x;
    const int wave  = tid >> 6, lane = tid & 63;
    const float* base = normals + (size_t)b * NPTS * 3;

    // Build the w(d) table (one-time; exact poly path).
    for (int e = tid; e < 2049; e += NPTS)
        wtab[e] = pair_w_exact((float)e * (1.f / 1024.f) - 1.f);
    for (int k = tid; k < NPTS * 3; k += NPTS) {
        float val = base[k];
        int r = k / 3, c = k - r * 3;
        float* dst = (c == 0) ? sx : (c == 1) ? sy : sz;
        dst[r] = val;
    }
    racc[tid] = 0.f;
    __syncthreads();

    const float xi = sx[tid], yi = sy[tid], zi = sz[tid];
    float accA = 0.f;

    // R6-verified schedule split into two balanced 128-step halves.
    if (half == 0) {
        do_seg<1, 31, true >(sx, sy, sz, wtab, wave,           lane, xi, yi, zi, accA, racc);
        do_seg<0, 63, false>(sx, sy, sz, wtab, (wave + 1) & 7, lane, xi, yi, zi, accA, racc);
        if (wave < 4) do_seg<0, 31, false>(sx, sy, sz, wtab, wave + 4, lane, xi, yi, zi, accA, racc);
        else          do_seg<1, 32, false>(sx, sy, sz, wtab, wave - 4, lane, xi, yi, zi, accA, racc);
    } else {
        do_seg<0, 63, false>(sx, sy, sz, wtab, (wave + 2) & 7, lane, xi, yi, zi, accA, racc);
        do_seg<0, 63, false>(sx, sy, sz, wtab, (wave + 3) & 7, lane, xi, yi, zi, accA, racc);
    }

    __syncthreads();
    float s = accA + racc[tid];   // partial row sum (this block's pairs only)

    // Global-max division skipped: uniform positive scale cancels under the
    // final normalization (verified R0-R13).
    float ax = s * xi, ay = s * yi, az = s * zi;

    for (int off = 32; off > 0; off >>= 1) {
        ax += __shfl_down(ax, off, 64);
        ay += __shfl_down(ay, off, 64);
        az += __shfl_down(az, off, 64);
    }
    if (lane == 0) { rx[wave] = ax; ry[wave] = ay; rz[wave] = az; }
    __syncthreads();

    if (tid == 0) {
        float nx = 0.f, ny = 0.f, nz = 0.f;
        #pragma unroll
        for (int w = 0; w < 8; ++w) { nx += rx[w]; ny += ry[w]; nz += rz[w]; }
        ((float4*)ws)[bx_id] = make_float4(nx, ny, nz, 0.f);  // no atomics
    }
}

__global__ __launch_bounds__(512) void norm_kernel(
    const float* __restrict__ ws, float* __restrict__ out)
{
    const int t = threadIdx.x;    // one thread per batch
    float4 p0 = ((const float4*)ws)[2 * t];
    float4 p1 = ((const float4*)ws)[2 * t + 1];
    float nx = p0.x + p1.x, ny = p0.y + p1.y, nz = p0.z + p1.z;
    float len2 = fmaf(nx, nx, fmaf(ny, ny, nz * nz));
    float inv  = rsqrtf(fmaxf(len2, 1e-20f));
    out[t * 3 + 0] = nx * inv;
    out[t * 3 + 1] = ny * inv;
    out[t * 3 + 2] = nz * inv;
}

extern "C" void kernel_launch(void* const* d_in, const int* in_sizes, int n_in,
                              void* d_out, int out_size, void* d_ws, size_t ws_size,
                              hipStream_t stream) {
    const float* normals = (const float*)d_in[0];
    // d_in[1] (weights) is mathematically unused by the reference.
    float* out = (float*)d_out;
    float* ws  = (float*)d_ws;
    pairs_kernel<<<2 * BATCH, NPTS, 0, stream>>>(normals, ws);
    norm_kernel<<<1, BATCH, 0, stream>>>(ws, out);
}